// Round 4
// baseline (428.107 us; speedup 1.0000x reference)
//
#include <hip/hip_runtime.h>
#include <math.h>

// Problem constants: b=2, h=16, s=4096, d=64, m=256
#define D 64
#define M 256
#define NTOK 131072ull                 // tokens per tensor (b*h*s)
#define QOUT_ELEMS 33554432ull         // 2*16*4096*256 (q' flat size)

constexpr float DATA_NORM  = 0.35355339059327373f;  // 64^-0.25
constexpr float DIAG_SCALE = 0.0625f;               // 0.5 * 64^-0.5
constexpr float RATIO      = 0.0625f;               // 256^-0.5
constexpr float EPS_F      = 1e-4f;

// ---------- K0: transpose projection [256][64] -> projT [64][256] in ws ----------
__global__ __launch_bounds__(256) void k0_transpose(const float* __restrict__ proj,
                                                    float* __restrict__ projT) {
    int i = blockIdx.x * 256 + threadIdx.x;   // 0..16383
    int m = i >> 6, d = i & 63;
    projT[d * M + m] = proj[i];
}

// ---------- K1: main fused matmul ----------
// blocks 0..511   : q tokens  (writes final q')
// blocks 512..1023: k tokens  (writes k_dash - diag; partial max per block)
__global__ __launch_bounds__(256, 2) void k1_main(
    const float* __restrict__ qin, const float* __restrict__ kin,
    const float* __restrict__ projT, float* __restrict__ out,
    float* __restrict__ partial_max)
{
    __shared__ float proj_lds[D * M];       // 64 KB, [d][m]
    __shared__ float x_lds[4][16][D];       // 16 KB, per-wave [token][d]

    const int tid  = threadIdx.x;
    const int lane = tid & 63;
    const int wave = tid >> 6;
    const int bid  = blockIdx.x;
    const bool is_q = (bid < 512);
    const float* __restrict__ src = is_q ? qin : kin;
    const int tb = is_q ? bid : (bid - 512);
    float* __restrict__ outbase = out + (is_q ? 0ull : QOUT_ELEMS);

    // stage projT into LDS (coalesced, conflict-free)
    {
        const float4* g = (const float4*)projT;
        float4* l = (float4*)proj_lds;
        #pragma unroll
        for (int i = 0; i < 16; ++i) l[i * 256 + tid] = g[i * 256 + tid];
    }
    __syncthreads();

    float blockmax = -INFINITY;   // k only

    for (int pass = 0; pass < 4; ++pass) {
        const int token0 = tb * 256 + pass * 64 + wave * 16;

        // ---- stage 16 tokens x 64 floats (4 KB contiguous) ----
        const float4* g = (const float4*)(src + (size_t)token0 * D);
        float4* xl = (float4*)(&x_lds[wave][0][0]);
        float4 xv[4];
        #pragma unroll
        for (int kk = 0; kk < 4; ++kk) xv[kk] = g[kk * 64 + lane];
        #pragma unroll
        for (int kk = 0; kk < 4; ++kk) xl[kk * 64 + lane] = xv[kk];

        // ---- diag = ||x||^2 * 0.5 * dn^2, from staging regs ----
        // lane l, load kk covers token (4*kk + l/16), d-range (l%16)*4..+3
        float dsum[4];
        #pragma unroll
        for (int kk = 0; kk < 4; ++kk)
            dsum[kk] = xv[kk].x*xv[kk].x + xv[kk].y*xv[kk].y
                     + xv[kk].z*xv[kk].z + xv[kk].w*xv[kk].w;
        #pragma unroll
        for (int off = 1; off < 16; off <<= 1) {
            #pragma unroll
            for (int kk = 0; kk < 4; ++kk)
                dsum[kk] += __shfl_xor(dsum[kk], off);
        }
        float diag[16];
        #pragma unroll
        for (int tt = 0; tt < 16; ++tt)
            diag[tt] = __shfl(dsum[tt >> 2], (tt & 3) * 16) * DIAG_SCALE;

        __syncthreads();   // x_lds visible

        // ---- matmul: acc[tt][0..3] = x[tt] . projT[:, 4*lane .. 4*lane+3] ----
        float4 acc[16];
        #pragma unroll
        for (int tt = 0; tt < 16; ++tt) acc[tt] = make_float4(0.f, 0.f, 0.f, 0.f);

        for (int d4 = 0; d4 < 16; ++d4) {
            float4 pv[4];
            #pragma unroll
            for (int i = 0; i < 4; ++i)
                pv[i] = *(const float4*)&proj_lds[(4 * d4 + i) * M + 4 * lane];
            #pragma unroll
            for (int tt = 0; tt < 16; ++tt) {
                float4 xq = *(const float4*)&x_lds[wave][tt][4 * d4];  // broadcast
                acc[tt].x = fmaf(pv[0].x, xq.x, acc[tt].x);
                acc[tt].y = fmaf(pv[0].y, xq.x, acc[tt].y);
                acc[tt].z = fmaf(pv[0].z, xq.x, acc[tt].z);
                acc[tt].w = fmaf(pv[0].w, xq.x, acc[tt].w);
                acc[tt].x = fmaf(pv[1].x, xq.y, acc[tt].x);
                acc[tt].y = fmaf(pv[1].y, xq.y, acc[tt].y);
                acc[tt].z = fmaf(pv[1].z, xq.y, acc[tt].z);
                acc[tt].w = fmaf(pv[1].w, xq.y, acc[tt].w);
                acc[tt].x = fmaf(pv[2].x, xq.z, acc[tt].x);
                acc[tt].y = fmaf(pv[2].y, xq.z, acc[tt].y);
                acc[tt].z = fmaf(pv[2].z, xq.z, acc[tt].z);
                acc[tt].w = fmaf(pv[2].w, xq.z, acc[tt].w);
                acc[tt].x = fmaf(pv[3].x, xq.w, acc[tt].x);
                acc[tt].y = fmaf(pv[3].y, xq.w, acc[tt].y);
                acc[tt].z = fmaf(pv[3].z, xq.w, acc[tt].z);
                acc[tt].w = fmaf(pv[3].w, xq.w, acc[tt].w);
            }
        }

        // ---- epilogue ----
        if (is_q) {
            #pragma unroll
            for (int tt = 0; tt < 16; ++tt) {
                float4 dd;
                dd.x = acc[tt].x * DATA_NORM;
                dd.y = acc[tt].y * DATA_NORM;
                dd.z = acc[tt].z * DATA_NORM;
                dd.w = acc[tt].w * DATA_NORM;
                float mx = fmaxf(fmaxf(dd.x, dd.y), fmaxf(dd.z, dd.w));
                #pragma unroll
                for (int off = 1; off < 64; off <<= 1)
                    mx = fmaxf(mx, __shfl_xor(mx, off));
                const float c = diag[tt] + mx;   // exp(dd - diag - stab)
                float4 o;
                o.x = RATIO * (expf(dd.x - c) + EPS_F);
                o.y = RATIO * (expf(dd.y - c) + EPS_F);
                o.z = RATIO * (expf(dd.z - c) + EPS_F);
                o.w = RATIO * (expf(dd.w - c) + EPS_F);
                ((float4*)outbase)[(size_t)(token0 + tt) * 64 + lane] = o;
            }
        } else {
            #pragma unroll
            for (int tt = 0; tt < 16; ++tt) {
                float4 dd;
                dd.x = acc[tt].x * DATA_NORM;
                dd.y = acc[tt].y * DATA_NORM;
                dd.z = acc[tt].z * DATA_NORM;
                dd.w = acc[tt].w * DATA_NORM;
                blockmax = fmaxf(blockmax, fmaxf(fmaxf(dd.x, dd.y), fmaxf(dd.z, dd.w)));
                float4 o;   // store data_dash - diag (stab applied in K3)
                o.x = dd.x - diag[tt];
                o.y = dd.y - diag[tt];
                o.z = dd.z - diag[tt];
                o.w = dd.w - diag[tt];
                ((float4*)outbase)[(size_t)(token0 + tt) * 64 + lane] = o;
            }
        }
        __syncthreads();   // protect x_lds before next pass's staging
    }

    if (!is_q) {
        #pragma unroll
        for (int off = 1; off < 64; off <<= 1)
            blockmax = fmaxf(blockmax, __shfl_xor(blockmax, off));
        if (lane == 0) x_lds[0][0][wave] = blockmax;
        __syncthreads();
        if (tid == 0) {
            float m0 = fmaxf(fmaxf(x_lds[0][0][0], x_lds[0][0][1]),
                             fmaxf(x_lds[0][0][2], x_lds[0][0][3]));
            partial_max[bid - 512] = m0;
        }
    }
}

// ---------- K2: reduce 512 block-partials -> stab[32] (16 partials per bh) ----------
__global__ void k2_reduce(const float* __restrict__ partial, float* __restrict__ stab) {
    int tid = threadIdx.x;   // 512 threads
    float v = partial[tid];
    #pragma unroll
    for (int off = 1; off < 16; off <<= 1)
        v = fmaxf(v, __shfl_xor(v, off));
    if ((tid & 15) == 0) stab[tid >> 4] = v;
}

// ---------- K3: k' fix-up: out = ratio * (exp(v - stab[bh]) + eps) ----------
__global__ __launch_bounds__(256) void k3_fix(float* __restrict__ outk,
                                              const float* __restrict__ stab) {
    const int bid = blockIdx.x;            // 2048 blocks, 4096 float4 each (one bh per block)
    const float st = stab[bid >> 6];       // 64 blocks per (b,h)
    float4* p = (float4*)outk + (size_t)bid * 4096;
    const int tid = threadIdx.x;
    #pragma unroll 4
    for (int it = 0; it < 16; ++it) {
        float4 v = p[it * 256 + tid];
        float4 o;
        o.x = RATIO * (expf(v.x - st) + EPS_F);
        o.y = RATIO * (expf(v.y - st) + EPS_F);
        o.z = RATIO * (expf(v.z - st) + EPS_F);
        o.w = RATIO * (expf(v.w - st) + EPS_F);
        p[it * 256 + tid] = o;
    }
}

extern "C" void kernel_launch(void* const* d_in, const int* in_sizes, int n_in,
                              void* d_out, int out_size, void* d_ws, size_t ws_size,
                              hipStream_t stream) {
    const float* q    = (const float*)d_in[0];
    const float* k    = (const float*)d_in[1];
    const float* proj = (const float*)d_in[2];
    float* out = (float*)d_out;
    float* ws  = (float*)d_ws;

    float* projT   = ws;                   // 16384 floats
    float* partial = ws + 16384;           // 512 floats
    float* stab    = ws + 16384 + 512;     // 32 floats

    k0_transpose<<<64,   256, 0, stream>>>(proj, projT);
    k1_main     <<<1024, 256, 0, stream>>>(q, k, projT, out, partial);
    k2_reduce   <<<1,    512, 0, stream>>>(partial, stab);
    k3_fix      <<<2048, 256, 0, stream>>>(out + QOUT_ELEMS, stab);
}

// Round 7
// 423.940 us; speedup vs baseline: 1.0098x; 1.0098x over previous
//
#include <hip/hip_runtime.h>
#include <math.h>

// Problem constants: b=2, h=16, s=4096, d=64, m=256
#define D 64
#define M 256
#define QOUT_ELEMS 33554432ull         // 2*16*4096*256 (q' flat size)

constexpr float DATA_NORM = 0.35355339059327373f;   // 64^-0.25
constexpr float L2E       = 1.4426950408889634f;    // log2(e)
constexpr float DN_L2E    = DATA_NORM * L2E;        // data_dash scale, log2 domain
constexpr float DIAG_L2E  = 0.0625f * L2E;          // 0.5*dn^2 * log2e
constexpr float RATIO     = 0.0625f;                // 256^-0.5
constexpr float EPS_F     = 1e-4f;

// ---------- K0: transpose projection [256][64] -> projT [64][256] in ws ----------
__global__ __launch_bounds__(256) void k0_transpose(const float* __restrict__ proj,
                                                    float* __restrict__ projT) {
    int i = blockIdx.x * 256 + threadIdx.x;   // 0..16383
    int m = i >> 6, d = i & 63;
    projT[d * M + m] = proj[i];
}

// ---------- K1: main fused matmul ----------
// 512 threads (8 waves), 80KB LDS -> 2 blocks/CU, 16 waves/CU (4/SIMD).
// blocks 0..511: q (final q'); blocks 512..1023: k (dd_l2e - diag_l2e; partial max).
// Everything in log2 domain: dd_l2e = (x.P)*DATA_NORM*L2E, exp -> exp2.
__global__ __launch_bounds__(512, 4) void k1_main(
    const float* __restrict__ qin, const float* __restrict__ kin,
    const float* __restrict__ projT, float* __restrict__ out,
    float* __restrict__ partial_max)
{
    __shared__ float proj_lds[D * M];      // 64 KB, [d][m]
    __shared__ float x_lds[8][8][D];       // 16 KB, [wave][token][d]

    const int tid  = threadIdx.x;
    const int lane = tid & 63;
    const int wave = tid >> 6;
    const int bid  = blockIdx.x;
    const bool is_q = (bid < 512);
    const float* __restrict__ src = is_q ? qin : kin;
    const int tb = is_q ? bid : (bid - 512);
    float* __restrict__ outbase = out + (is_q ? 0ull : QOUT_ELEMS);

    // stage projT into LDS: 4096 float4 over 512 threads
    {
        const float4* g = (const float4*)projT;
        float4* l = (float4*)proj_lds;
        #pragma unroll
        for (int i = 0; i < 8; ++i) l[i * 512 + tid] = g[i * 512 + tid];
    }
    __syncthreads();

    float blockmax = -INFINITY;   // k only (log2 domain)

    for (int pass = 0; pass < 4; ++pass) {
        const int token0 = tb * 256 + pass * 64 + wave * 8;

        // ---- stage 8 tokens x 64 floats = 128 float4 (2 KB contiguous per wave) ----
        const float4* g = (const float4*)(src + (size_t)token0 * D);
        float4* xl = (float4*)(&x_lds[wave][0][0]);
        float4 xv[2];
        #pragma unroll
        for (int kk = 0; kk < 2; ++kk) xv[kk] = g[kk * 64 + lane];
        #pragma unroll
        for (int kk = 0; kk < 2; ++kk) xl[kk * 64 + lane] = xv[kk];

        // ---- diag (log2 domain) from staging regs ----
        // flat f4 idx kk*64+lane: token = kk*4 + (lane>>4), d4 = lane&15
        float dsum[2];
        #pragma unroll
        for (int kk = 0; kk < 2; ++kk)
            dsum[kk] = xv[kk].x*xv[kk].x + xv[kk].y*xv[kk].y
                     + xv[kk].z*xv[kk].z + xv[kk].w*xv[kk].w;
        #pragma unroll
        for (int off = 1; off < 16; off <<= 1) {
            #pragma unroll
            for (int kk = 0; kk < 2; ++kk)
                dsum[kk] += __shfl_xor(dsum[kk], off);
        }
        float diag[8];
        #pragma unroll
        for (int tt = 0; tt < 8; ++tt)
            diag[tt] = __shfl(dsum[tt >> 2], (tt & 3) * 16) * DIAG_L2E;

        __syncthreads();   // x_lds visible

        // ---- matmul: acc[tt] = x[tt] . projT[:, 4*lane .. 4*lane+3] ----
        float4 acc[8];
        #pragma unroll
        for (int tt = 0; tt < 8; ++tt) acc[tt] = make_float4(0.f, 0.f, 0.f, 0.f);

        for (int d4 = 0; d4 < 16; ++d4) {
            float4 pv[4];
            #pragma unroll
            for (int i = 0; i < 4; ++i)
                pv[i] = *(const float4*)&proj_lds[(4 * d4 + i) * M + 4 * lane];
            #pragma unroll
            for (int tt = 0; tt < 8; ++tt) {
                float4 xq = *(const float4*)&x_lds[wave][tt][4 * d4];  // broadcast
                acc[tt].x = fmaf(pv[0].x, xq.x, acc[tt].x);
                acc[tt].y = fmaf(pv[0].y, xq.x, acc[tt].y);
                acc[tt].z = fmaf(pv[0].z, xq.x, acc[tt].z);
                acc[tt].w = fmaf(pv[0].w, xq.x, acc[tt].w);
                acc[tt].x = fmaf(pv[1].x, xq.y, acc[tt].x);
                acc[tt].y = fmaf(pv[1].y, xq.y, acc[tt].y);
                acc[tt].z = fmaf(pv[1].z, xq.y, acc[tt].z);
                acc[tt].w = fmaf(pv[1].w, xq.y, acc[tt].w);
                acc[tt].x = fmaf(pv[2].x, xq.z, acc[tt].x);
                acc[tt].y = fmaf(pv[2].y, xq.z, acc[tt].y);
                acc[tt].z = fmaf(pv[2].z, xq.z, acc[tt].z);
                acc[tt].w = fmaf(pv[2].w, xq.z, acc[tt].w);
                acc[tt].x = fmaf(pv[3].x, xq.w, acc[tt].x);
                acc[tt].y = fmaf(pv[3].y, xq.w, acc[tt].y);
                acc[tt].z = fmaf(pv[3].z, xq.w, acc[tt].z);
                acc[tt].w = fmaf(pv[3].w, xq.w, acc[tt].w);
            }
        }

        // ---- epilogue (log2 domain) ----
        if (is_q) {
            #pragma unroll
            for (int tt = 0; tt < 8; ++tt) {
                float4 dd;
                dd.x = acc[tt].x * DN_L2E;
                dd.y = acc[tt].y * DN_L2E;
                dd.z = acc[tt].z * DN_L2E;
                dd.w = acc[tt].w * DN_L2E;
                float mx = fmaxf(fmaxf(dd.x, dd.y), fmaxf(dd.z, dd.w));
                #pragma unroll
                for (int off = 1; off < 64; off <<= 1)
                    mx = fmaxf(mx, __shfl_xor(mx, off));
                const float c = diag[tt] + mx;
                float4 o;
                o.x = RATIO * (exp2f(dd.x - c) + EPS_F);
                o.y = RATIO * (exp2f(dd.y - c) + EPS_F);
                o.z = RATIO * (exp2f(dd.z - c) + EPS_F);
                o.w = RATIO * (exp2f(dd.w - c) + EPS_F);
                ((float4*)outbase)[(size_t)(token0 + tt) * 64 + lane] = o;
            }
        } else {
            #pragma unroll
            for (int tt = 0; tt < 8; ++tt) {
                float4 dd;
                dd.x = acc[tt].x * DN_L2E;
                dd.y = acc[tt].y * DN_L2E;
                dd.z = acc[tt].z * DN_L2E;
                dd.w = acc[tt].w * DN_L2E;
                blockmax = fmaxf(blockmax, fmaxf(fmaxf(dd.x, dd.y), fmaxf(dd.z, dd.w)));
                float4 o;   // store dd_l2e - diag_l2e (stab applied in K3)
                o.x = dd.x - diag[tt];
                o.y = dd.y - diag[tt];
                o.z = dd.z - diag[tt];
                o.w = dd.w - diag[tt];
                ((float4*)outbase)[(size_t)(token0 + tt) * 64 + lane] = o;
            }
        }
        __syncthreads();   // protect x_lds before next pass's staging
    }

    if (!is_q) {
        #pragma unroll
        for (int off = 1; off < 64; off <<= 1)
            blockmax = fmaxf(blockmax, __shfl_xor(blockmax, off));
        if (lane == 0) x_lds[0][0][wave] = blockmax;   // 8 per-wave maxes
        __syncthreads();
        if (tid == 0) {
            float m0 = -INFINITY;
            #pragma unroll
            for (int w = 0; w < 8; ++w) m0 = fmaxf(m0, x_lds[0][0][w]);
            partial_max[tb] = m0;
        }
    }
}

// ---------- K3: k' fix-up (K2 folded in): out = ratio*(exp2(v - stab[bh]) + eps) ----------
__global__ __launch_bounds__(256) void k3_fix(float* __restrict__ outk,
                                              const float* __restrict__ partial) {
    const int bid = blockIdx.x;            // 2048 blocks, one (b,h)-64th each
    const int bh  = bid >> 6;              // 64 blocks per (b,h)
    const int tid = threadIdx.x;
    // stab = max of this bh's 16 block-partials; every lane reads one, 16-group reduce
    float v = partial[bh * 16 + (tid & 15)];
    #pragma unroll
    for (int off = 1; off < 16; off <<= 1)
        v = fmaxf(v, __shfl_xor(v, off));
    const float st = v;                    // uniform across all lanes

    float4* p = (float4*)outk + (size_t)bid * 4096;
    #pragma unroll 4
    for (int it = 0; it < 16; ++it) {
        float4 w = p[it * 256 + tid];
        float4 o;
        o.x = RATIO * (exp2f(w.x - st) + EPS_F);
        o.y = RATIO * (exp2f(w.y - st) + EPS_F);
        o.z = RATIO * (exp2f(w.z - st) + EPS_F);
        o.w = RATIO * (exp2f(w.w - st) + EPS_F);
        p[it * 256 + tid] = o;
    }
}

extern "C" void kernel_launch(void* const* d_in, const int* in_sizes, int n_in,
                              void* d_out, int out_size, void* d_ws, size_t ws_size,
                              hipStream_t stream) {
    const float* q    = (const float*)d_in[0];
    const float* k    = (const float*)d_in[1];
    const float* proj = (const float*)d_in[2];
    float* out = (float*)d_out;
    float* ws  = (float*)d_ws;

    float* projT   = ws;                   // 16384 floats
    float* partial = ws + 16384;           // 512 floats

    k0_transpose<<<64,   256, 0, stream>>>(proj, projT);
    k1_main     <<<1024, 512, 0, stream>>>(q, k, projT, out, partial);
    k3_fix      <<<2048, 256, 0, stream>>>(out + QOUT_ELEMS, partial);
}